// Round 1
// baseline (2269.183 us; speedup 1.0000x reference)
//
#include <hip/hip_runtime.h>
#include <math.h>

constexpr int D  = 256;   // feature dim
constexpr int BM = 128;   // rows per block
constexpr int BN = 128;   // codewords per tile
constexpr int DT = 16;    // d-chunk staged in LDS
constexpr int TM = 8;     // rows per thread
constexpr int TN = 8;     // codewords per thread

// -------- codeword squared norms --------
__global__ void vq_csq(const float* __restrict__ cw, float* __restrict__ csq) {
    int k = blockIdx.x * blockDim.x + threadIdx.x;
    const float4* p = reinterpret_cast<const float4*>(cw + (size_t)k * D);
    float s = 0.f;
    #pragma unroll 8
    for (int i = 0; i < D / 4; ++i) {
        float4 v = p[i];
        s += v.x * v.x;
        s += v.y * v.y;
        s += v.z * v.z;
        s += v.w * v.w;
    }
    csq[k] = s;
}

// -------- main: distances + argmin + gather + loss partial --------
__launch_bounds__(256, 2)
__global__ void vq_main(const float* __restrict__ inp,
                        const float* __restrict__ cw,
                        const float* __restrict__ csq,
                        float* __restrict__ outq,
                        float* __restrict__ outi,
                        float* __restrict__ bsum,
                        int K) {
    __shared__ float xs[DT][BM];
    __shared__ float cs[DT][BN];
    __shared__ int   s_bidx[BM];
    __shared__ float s_loss[4];

    const int tid  = threadIdx.x;
    const int tx   = tid & 15;        // codeword group
    const int ty   = tid >> 4;        // row group
    const int lane = tid & 63;
    const int wave = tid >> 6;
    const int r0   = blockIdx.x * BM;

    float minv[TM];
    int   mini[TM];
    float xsq[TM];
    #pragma unroll
    for (int i = 0; i < TM; ++i) { minv[i] = INFINITY; mini[i] = 0; xsq[i] = 0.f; }

    for (int kt = 0; kt < K; kt += BN) {
        float acc[TM][TN];
        #pragma unroll
        for (int i = 0; i < TM; ++i)
            #pragma unroll
            for (int j = 0; j < TN; ++j) acc[i][j] = 0.f;

        for (int dt = 0; dt < D; dt += DT) {
            // load (coalesced along d), then register-transpose into [d][r] LDS
            float4 vx[2], vc[2];
            #pragma unroll
            for (int i = 0; i < 2; ++i) {
                int fidx = i * 256 + tid;   // 0..511 float4s per tile
                int r  = fidx >> 2;         // 0..127
                int dd = (fidx & 3) * 4;    // 0,4,8,12
                vx[i] = *reinterpret_cast<const float4*>(inp + (size_t)(r0 + r) * D + dt + dd);
                vc[i] = *reinterpret_cast<const float4*>(cw  + (size_t)(kt + r) * D + dt + dd);
            }
            __syncthreads();   // previous compute done before overwrite
            #pragma unroll
            for (int i = 0; i < 2; ++i) {
                int fidx = i * 256 + tid;
                int r  = fidx >> 2;
                int dd = (fidx & 3) * 4;
                xs[dd + 0][r] = vx[i].x;
                xs[dd + 1][r] = vx[i].y;
                xs[dd + 2][r] = vx[i].z;
                xs[dd + 3][r] = vx[i].w;
                cs[dd + 0][r] = vc[i].x;
                cs[dd + 1][r] = vc[i].y;
                cs[dd + 2][r] = vc[i].z;
                cs[dd + 3][r] = vc[i].w;
            }
            __syncthreads();

            #pragma unroll
            for (int d = 0; d < DT; ++d) {
                float a[TM], b[TN];
                float4 a0 = *reinterpret_cast<const float4*>(&xs[d][ty * TM]);
                float4 a1 = *reinterpret_cast<const float4*>(&xs[d][ty * TM + 4]);
                float4 b0 = *reinterpret_cast<const float4*>(&cs[d][tx * TN]);
                float4 b1 = *reinterpret_cast<const float4*>(&cs[d][tx * TN + 4]);
                a[0] = a0.x; a[1] = a0.y; a[2] = a0.z; a[3] = a0.w;
                a[4] = a1.x; a[5] = a1.y; a[6] = a1.z; a[7] = a1.w;
                b[0] = b0.x; b[1] = b0.y; b[2] = b0.z; b[3] = b0.w;
                b[4] = b1.x; b[5] = b1.y; b[6] = b1.z; b[7] = b1.w;
                if (kt == 0) {
                    #pragma unroll
                    for (int i = 0; i < TM; ++i) xsq[i] += a[i] * a[i];
                }
                #pragma unroll
                for (int i = 0; i < TM; ++i)
                    #pragma unroll
                    for (int j = 0; j < TN; ++j)
                        acc[i][j] += a[i] * b[j];
            }
        }

        // distances for this codeword tile + running argmin
        #pragma unroll
        for (int j = 0; j < TN; ++j) {
            int kk = kt + tx * TN + j;
            float cq = csq[kk];
            #pragma unroll
            for (int i = 0; i < TM; ++i) {
                float m2   = acc[i][j] + acc[i][j];  // 2*dot (exact, avoids fma contraction)
                float t    = xsq[i] - m2;            // match ref association
                float dval = t + cq;
                if (dval < minv[i]) { minv[i] = dval; mini[i] = kk; }  // ascending kk -> first-min wins
            }
        }
    }

    // reduce argmin across the 16 tx-threads sharing each row (within-wave groups of 16)
    #pragma unroll
    for (int i = 0; i < TM; ++i) {
        float v  = minv[i];
        int   ix = mini[i];
        #pragma unroll
        for (int off = 8; off; off >>= 1) {
            float ov = __shfl_xor(v, off, 16);
            int   oi = __shfl_xor(ix, off, 16);
            if (ov < v || (ov == v && oi < ix)) { v = ov; ix = oi; }
        }
        if (tx == 0) {
            int row = ty * TM + i;
            s_bidx[row] = ix;
            outi[r0 + row] = (float)ix;
        }
    }
    __syncthreads();

    // gather winning codewords -> output, accumulate loss partial
    float lacc = 0.f;
    #pragma unroll 4
    for (int it = 0; it < BM / 4; ++it) {
        int row = it * 4 + wave;           // one full row per wave per iter
        int k   = s_bidx[row];             // wave-uniform broadcast
        float4 c = *reinterpret_cast<const float4*>(cw  + (size_t)k * D + lane * 4);
        float4 x = *reinterpret_cast<const float4*>(inp + (size_t)(r0 + row) * D + lane * 4);
        *reinterpret_cast<float4*>(outq + (size_t)(r0 + row) * D + lane * 4) = c;
        float dx = c.x - x.x, dy = c.y - x.y, dz = c.z - x.z, dw = c.w - x.w;
        lacc += dx * dx + dy * dy + dz * dz + dw * dw;
    }
    #pragma unroll
    for (int off = 32; off; off >>= 1) lacc += __shfl_down(lacc, off, 64);
    if (lane == 0) s_loss[wave] = lacc;
    __syncthreads();
    if (tid == 0) bsum[blockIdx.x] = s_loss[0] + s_loss[1] + s_loss[2] + s_loss[3];
}

// -------- deterministic loss reduction --------
__global__ void vq_finalize(const float* __restrict__ bsum, float* __restrict__ out_loss,
                            int nb, float scale) {
    __shared__ float s[4];
    int tid = threadIdx.x;
    float v = 0.f;
    for (int i = tid; i < nb; i += 256) v += bsum[i];
    #pragma unroll
    for (int off = 32; off; off >>= 1) v += __shfl_down(v, off, 64);
    if ((tid & 63) == 0) s[tid >> 6] = v;
    __syncthreads();
    if (tid == 0) out_loss[0] = (s[0] + s[1] + s[2] + s[3]) * scale;
}

extern "C" void kernel_launch(void* const* d_in, const int* in_sizes, int n_in,
                              void* d_out, int out_size, void* d_ws, size_t ws_size,
                              hipStream_t stream) {
    const float* inp = (const float*)d_in[0];
    const float* cw  = (const float*)d_in[1];
    float* out = (float*)d_out;
    const int N = in_sizes[0] / D;     // 65536 rows
    const int K = in_sizes[1] / D;     // 1024 codewords

    float* ws       = (float*)d_ws;
    float* csq      = ws + 16;         // K floats
    float* bsum     = ws + 16 + K;     // N/BM floats
    float* outq     = out;
    float* outi     = out + (size_t)N * D;
    float* outl     = out + (size_t)N * D + N;

    const int nblocks = N / BM;        // 512

    vq_csq<<<dim3(K / 256), dim3(256), 0, stream>>>(cw, csq);
    vq_main<<<dim3(nblocks), dim3(256), 0, stream>>>(inp, cw, csq, outq, outi, bsum, K);
    vq_finalize<<<dim3(1), dim3(256), 0, stream>>>(bsum, outl, nblocks,
                                                   1.25f / ((float)N * (float)D));
}

// Round 5
// 264.925 us; speedup vs baseline: 8.5654x; 8.5654x over previous
//
#include <hip/hip_runtime.h>
#include <math.h>

typedef short v8s __attribute__((ext_vector_type(8)));
typedef float v4f __attribute__((ext_vector_type(4)));

constexpr int D       = 256;    // feature dim
constexpr int BM      = 128;    // rows per block (approx kernel)
constexpr int NT      = 32;     // codeword tiles (1024 / 32)
constexpr int TILE_B  = 32768;  // bytes per staged tile (hi split + lo split)
constexpr int SPLIT_B = 16384;  // bytes per split (32 cw x 256 d x 2B)

__device__ __forceinline__ unsigned short f2bf(float x) {   // RNE float->bf16 bits
    unsigned u = __float_as_uint(x);
    u += 0x7FFFu + ((u >> 16) & 1u);
    return (unsigned short)(u >> 16);
}
__device__ __forceinline__ float bf2f(unsigned short h) {
    return __uint_as_float(((unsigned)h) << 16);
}

// compare-exchange on (value,index) pairs, ascending, index tie-break
#define CESWAP(av, ai, bv, bi)                                         \
    { bool _t = (bv < av) || (bv == av && bi < ai);                    \
      float _v = _t ? bv : av; int _x = _t ? bi : ai;                  \
      bv = _t ? av : bv; bi = _t ? ai : bi; av = _v; ai = _x; }

// ---- pre-pass: codewords -> hi/lo bf16 in the pre-swizzled LDS-image layout ----
// Tile t (32 codewords), row c, 16B chunk cb: byte = t*TILE_B + c*512 + ((cb*16) ^ ((c&7)<<4))
__global__ void vq_prep(const float* __restrict__ cw, unsigned short* __restrict__ wsB) {
    int gid = blockIdx.x * 256 + threadIdx.x;   // 1024 cw * 32 chunks = 32768
    int k  = gid >> 5;
    int cb = gid & 31;
    const float* src = cw + (size_t)k * D + cb * 8;
    v8s vh, vl;
    #pragma unroll
    for (int e = 0; e < 8; ++e) {
        float x = src[e];
        unsigned short h = f2bf(x);
        vh[e] = (short)h;
        vl[e] = (short)f2bf(x - bf2f(h));
    }
    int t = k >> 5, c = k & 31;
    size_t base = (size_t)t * TILE_B + (size_t)c * 512 + (size_t)((cb * 16) ^ ((c & 7) << 4));
    *(v8s*)((char*)wsB + base) = vh;
    *(v8s*)((char*)wsB + base + SPLIT_B) = vl;
}

// ---- codeword squared norms (fp32; IDENTICAL to round-1 code that passed) ----
__global__ void vq_csq(const float* __restrict__ cw, float* __restrict__ csq) {
    int k = blockIdx.x * blockDim.x + threadIdx.x;
    const float4* p = reinterpret_cast<const float4*>(cw + (size_t)k * D);
    float s = 0.f;
    #pragma unroll 8
    for (int i = 0; i < D / 4; ++i) {
        float4 v = p[i];
        s += v.x * v.x; s += v.y * v.y; s += v.z * v.z; s += v.w * v.w;
    }
    csq[k] = s;
}

// ---- approx phase: MFMA distances -> per-lane top3 -> global top8 -> cand[] ----
__launch_bounds__(256, 2)
__global__ void vq_mfma(const float* __restrict__ inp,
                        const unsigned short* __restrict__ wsB,
                        const float* __restrict__ csq,
                        int* __restrict__ cand) {
    extern __shared__ char smem[];

    const int tid  = threadIdx.x;
    const int lane = tid & 63;
    const int w    = tid >> 6;      // wave 0..3
    const int lr   = lane & 15;     // frag row/col
    const int q    = lane >> 4;     // k-chunk group
    const int r0   = blockIdx.x * BM;

    // stage tile 0 into buf0 (linear copy of pre-swizzled image)
    #pragma unroll
    for (int cl = 0; cl < 8; ++cl) {
        int off = cl * 4096 + w * 1024;
        __builtin_amdgcn_global_load_lds(
            (const __attribute__((address_space(1))) unsigned int*)((const char*)wsB + off + lane * 16),
            (__attribute__((address_space(3))) unsigned int*)(smem + off),
            16, 0, 0);
    }

    // load this wave's 32 rows of A, convert to bf16 hi/lo fragments in regs
    // A frag (16x16x32): lane holds row = lane&15, k = (lane>>4)*8 + e
    v8s a_hi[2][8], a_lo[2][8];
    #pragma unroll
    for (int m = 0; m < 2; ++m) {
        const float* rp = inp + (size_t)(r0 + w * 32 + m * 16 + lr) * D + q * 8;
        float4 ta[8], tb[8];
        #pragma unroll
        for (int j = 0; j < 8; ++j) {
            ta[j] = *(const float4*)(rp + j * 32);
            tb[j] = *(const float4*)(rp + j * 32 + 4);
        }
        #pragma unroll
        for (int j = 0; j < 8; ++j) {
            float f[8] = {ta[j].x, ta[j].y, ta[j].z, ta[j].w,
                          tb[j].x, tb[j].y, tb[j].z, tb[j].w};
            v8s h, l;
            #pragma unroll
            for (int e = 0; e < 8; ++e) {
                unsigned short hh = f2bf(f[e]);
                h[e] = (short)hh;
                l[e] = (short)f2bf(f[e] - bf2f(hh));
            }
            a_hi[m][j] = h; a_lo[m][j] = l;
        }
    }

    asm volatile("s_waitcnt vmcnt(0)" ::: "memory");
    __builtin_amdgcn_s_barrier();
    __builtin_amdgcn_sched_barrier(0);

    // per-lane running top-3 (sorted ascending) over this lane's candidate subset
    float v1[2][4], v2[2][4], v3[2][4];
    int   i1[2][4], i2[2][4], i3[2][4];
    #pragma unroll
    for (int m = 0; m < 2; ++m)
        #pragma unroll
        for (int r = 0; r < 4; ++r) {
            v1[m][r] = INFINITY; v2[m][r] = INFINITY; v3[m][r] = INFINITY;
            i1[m][r] = 0; i2[m][r] = 1; i3[m][r] = 2;
        }

    int cur = 0;
    for (int kt = 0; kt < NT; ++kt) {
        if (kt + 1 < NT) {   // stage next tile early (2-phase template)
            const char* srct = (const char*)wsB + (size_t)(kt + 1) * TILE_B;
            char* dst = smem + (cur ^ 1) * TILE_B;
            #pragma unroll
            for (int cl = 0; cl < 8; ++cl) {
                int off = cl * 4096 + w * 1024;
                __builtin_amdgcn_global_load_lds(
                    (const __attribute__((address_space(1))) unsigned int*)(srct + off + lane * 16),
                    (__attribute__((address_space(3))) unsigned int*)(dst + off),
                    16, 0, 0);
            }
        }
        float cq0 = csq[kt * 32 + lr];
        float cq1 = csq[kt * 32 + 16 + lr];

        v4f acc[2][2];
        #pragma unroll
        for (int m = 0; m < 2; ++m)
            #pragma unroll
            for (int n = 0; n < 2; ++n) { v4f z = {0.f, 0.f, 0.f, 0.f}; acc[m][n] = z; }

        const char* bb = smem + cur * TILE_B;
        #pragma unroll
        for (int j = 0; j < 8; ++j) {
            v8s bh[2], bl[2];
            #pragma unroll
            for (int n = 0; n < 2; ++n) {
                int c   = n * 16 + lr;
                int col = (j * 64 + q * 16) ^ ((c & 7) << 4);   // swizzled ds_read
                const char* p = bb + c * 512 + col;
                bh[n] = *(const v8s*)p;
                bl[n] = *(const v8s*)(p + SPLIT_B);
            }
            #pragma unroll
            for (int m = 0; m < 2; ++m)
                #pragma unroll
                for (int n = 0; n < 2; ++n) {
                    acc[m][n] = __builtin_amdgcn_mfma_f32_16x16x32_bf16(a_hi[m][j], bh[n], acc[m][n], 0, 0, 0);
                    acc[m][n] = __builtin_amdgcn_mfma_f32_16x16x32_bf16(a_hi[m][j], bl[n], acc[m][n], 0, 0, 0);
                    acc[m][n] = __builtin_amdgcn_mfma_f32_16x16x32_bf16(a_lo[m][j], bh[n], acc[m][n], 0, 0, 0);
                }
        }

        asm volatile("s_waitcnt vmcnt(0)" ::: "memory");   // next tile landed (hidden under MFMA)
        __builtin_amdgcn_s_barrier();
        __builtin_amdgcn_sched_barrier(0);

        // approx scores: s = csq[c] - 2*dot  (x^2 constant per row, irrelevant for argmin)
        // C/D layout: col = lane&15, row = (lane>>4)*4 + r
        #pragma unroll
        for (int m = 0; m < 2; ++m)
            #pragma unroll
            for (int n = 0; n < 2; ++n) {
                int   idx = kt * 32 + n * 16 + lr;
                float cq  = n ? cq1 : cq0;
                #pragma unroll
                for (int r = 0; r < 4; ++r) {
                    float s  = fmaf(-2.f, acc[m][n][r], cq);
                    bool  b1 = s < v1[m][r];
                    bool  b2 = s < v2[m][r];
                    bool  b3 = s < v3[m][r];
                    v3[m][r] = b2 ? v2[m][r] : (b3 ? s : v3[m][r]);
                    i3[m][r] = b2 ? i2[m][r] : (b3 ? idx : i3[m][r]);
                    v2[m][r] = b1 ? v1[m][r] : (b2 ? s : v2[m][r]);
                    i2[m][r] = b1 ? i1[m][r] : (b2 ? idx : i2[m][r]);
                    v1[m][r] = b1 ? s : v1[m][r];
                    i1[m][r] = b1 ? idx : i1[m][r];
                }
            }
        cur ^= 1;
    }

    // butterfly-merge per-lane sorted top-3 (padded to 8) into per-row global top-8
    #pragma unroll
    for (int m = 0; m < 2; ++m)
        #pragma unroll
        for (int r = 0; r < 4; ++r) {
            float mv[8]; int mi[8];
            mv[0] = v1[m][r]; mv[1] = v2[m][r]; mv[2] = v3[m][r];
            mi[0] = i1[m][r]; mi[1] = i2[m][r]; mi[2] = i3[m][r];
            #pragma unroll
            for (int p = 3; p < 8; ++p) { mv[p] = INFINITY; mi[p] = 3 + p; }
            #pragma unroll
            for (int off = 8; off; off >>= 1) {
                float pv[8]; int pi[8];
                #pragma unroll
                for (int k = 0; k < 8; ++k) {
                    pv[k] = __shfl_xor(mv[k], off, 16);
                    pi[k] = __shfl_xor(mi[k], off, 16);
                }
                float L[8]; int Li[8];
                #pragma unroll
                for (int k = 0; k < 8; ++k) {   // lowest-8 of union, bitonic order
                    float bv = pv[7 - k]; int bx = pi[7 - k];
                    bool t = (bv < mv[k]) || (bv == mv[k] && bx < mi[k]);
                    L[k]  = t ? bv : mv[k];
                    Li[k] = t ? bx : mi[k];
                }
                // bitonic sort-8 (3 stages)
                CESWAP(L[0], Li[0], L[4], Li[4]); CESWAP(L[1], Li[1], L[5], Li[5]);
                CESWAP(L[2], Li[2], L[6], Li[6]); CESWAP(L[3], Li[3], L[7], Li[7]);
                CESWAP(L[0], Li[0], L[2], Li[2]); CESWAP(L[1], Li[1], L[3], Li[3]);
                CESWAP(L[4], Li[4], L[6], Li[6]); CESWAP(L[5], Li[5], L[7], Li[7]);
                CESWAP(L[0], Li[0], L[1], Li[1]); CESWAP(L[2], Li[2], L[3], Li[3]);
                CESWAP(L[4], Li[4], L[5], Li[5]); CESWAP(L[6], Li[6], L[7], Li[7]);
                #pragma unroll
                for (int k = 0; k < 8; ++k) { mv[k] = L[k]; mi[k] = Li[k]; }
            }
            if (lr == 0) {
                int row = w * 32 + m * 16 + q * 4 + r;
                int4* dst = (int4*)(cand + (size_t)(r0 + row) * 8);
                dst[0] = make_int4(mi[0], mi[1], mi[2], mi[3]);
                dst[1] = make_int4(mi[4], mi[5], mi[6], mi[7]);
            }
        }
}

// ---- exact phase: round-1 arithmetic on the 8 candidates, 1 thread = 1 row ----
// dot & xsq: sequential fp32 FMA in ascending d (matches round 1 / BLAS k-order).
// distance: (xsq - (dot+dot)) + csq[k]  (exact round-1 expression, which passed).
__launch_bounds__(256)
__global__ void vq_exact(const float* __restrict__ inp,
                         const float* __restrict__ cw,
                         const float* __restrict__ csq,
                         const int* __restrict__ cand,
                         float* __restrict__ outq,
                         float* __restrict__ outi,
                         float* __restrict__ bsum) {
    __shared__ float s_l[4];
    const int tid = threadIdx.x;
    const int row = blockIdx.x * 256 + tid;

    const int4* cl4 = (const int4*)(cand + (size_t)row * 8);
    int4 ca = cl4[0], cb = cl4[1];
    int cd[8] = {ca.x, ca.y, ca.z, ca.w, cb.x, cb.y, cb.z, cb.w};

    const float4* xp = (const float4*)(inp + (size_t)row * D);
    float dot[8];
    #pragma unroll
    for (int c = 0; c < 8; ++c) dot[c] = 0.f;
    float xsq = 0.f;

    #pragma unroll 4
    for (int i = 0; i < D / 4; ++i) {
        float4 xv = xp[i];
        xsq = fmaf(xv.x, xv.x, xsq);
        xsq = fmaf(xv.y, xv.y, xsq);
        xsq = fmaf(xv.z, xv.z, xsq);
        xsq = fmaf(xv.w, xv.w, xsq);
        #pragma unroll
        for (int c = 0; c < 8; ++c) {
            float4 cv = *(const float4*)(cw + (size_t)cd[c] * D + i * 4);
            dot[c] = fmaf(xv.x, cv.x, dot[c]);
            dot[c] = fmaf(xv.y, cv.y, dot[c]);
            dot[c] = fmaf(xv.z, cv.z, dot[c]);
            dot[c] = fmaf(xv.w, cv.w, dot[c]);
        }
    }

    float bd = INFINITY;
    int   bi = 0x7FFFFFFF;
    #pragma unroll
    for (int c = 0; c < 8; ++c) {
        float m2 = dot[c] + dot[c];
        float t  = xsq - m2;
        float e  = t + csq[cd[c]];
        bool  tk = (e < bd) || (e == bd && cd[c] < bi);
        bd = tk ? e : bd;
        bi = tk ? cd[c] : bi;
    }

    // gather winner, write quantized, accumulate loss partial (round-1 style)
    const float4* wp = (const float4*)(cw + (size_t)bi * D);
    float4* op = (float4*)(outq + (size_t)row * D);
    float lacc = 0.f;
    #pragma unroll 4
    for (int i = 0; i < D / 4; ++i) {
        float4 xv = xp[i];
        float4 cv = wp[i];
        op[i] = cv;
        float dx = cv.x - xv.x, dy = cv.y - xv.y, dz = cv.z - xv.z, dw = cv.w - xv.w;
        lacc += dx * dx + dy * dy + dz * dz + dw * dw;
    }
    outi[row] = (float)bi;

    #pragma unroll
    for (int off = 32; off; off >>= 1) lacc += __shfl_xor(lacc, off);
    if ((tid & 63) == 0) s_l[tid >> 6] = lacc;
    __syncthreads();
    if (tid == 0) bsum[blockIdx.x] = s_l[0] + s_l[1] + s_l[2] + s_l[3];
}

// ---- deterministic loss reduction ----
__global__ void vq_finalize(const float* __restrict__ bsum, float* __restrict__ out_loss,
                            int nb, float scale) {
    __shared__ float s[4];
    int tid = threadIdx.x;
    float v = 0.f;
    for (int i = tid; i < nb; i += 256) v += bsum[i];
    #pragma unroll
    for (int off = 32; off; off >>= 1) v += __shfl_down(v, off, 64);
    if ((tid & 63) == 0) s[tid >> 6] = v;
    __syncthreads();
    if (tid == 0) out_loss[0] = (s[0] + s[1] + s[2] + s[3]) * scale;
}

extern "C" void kernel_launch(void* const* d_in, const int* in_sizes, int n_in,
                              void* d_out, int out_size, void* d_ws, size_t ws_size,
                              hipStream_t stream) {
    const float* inp = (const float*)d_in[0];
    const float* cw  = (const float*)d_in[1];
    float* out = (float*)d_out;
    const int N = in_sizes[0] / D;   // 65536
    const int K = in_sizes[1] / D;   // 1024

    char* ws = (char*)d_ws;
    unsigned short* wsB = (unsigned short*)ws;            // 1 MB: 32 tiles x 32 KB
    float* csq  = (float*)(ws + (size_t)NT * TILE_B);     // 4 KB
    float* bsum = csq + K;                                // 1 KB (256 partials)
    int*   cand = (int*)(bsum + 256);                     // N*8 ints = 2 MB

    float* outq = out;
    float* outi = out + (size_t)N * D;
    float* outl = outi + N;

    vq_prep<<<dim3((K * 32) / 256), dim3(256), 0, stream>>>(cw, wsB);
    vq_csq<<<dim3(K / 256), dim3(256), 0, stream>>>(cw, csq);

    size_t lds_bytes = 2 * TILE_B;
    vq_mfma<<<dim3(N / BM), dim3(256), lds_bytes, stream>>>(inp, wsB, csq, cand);
    vq_exact<<<dim3(N / 256), dim3(256), 0, stream>>>(inp, cw, csq, cand, outq, outi, bsum);
    vq_finalize<<<dim3(1), dim3(256), 0, stream>>>(bsum, outl, N / 256,
                                                   1.25f / ((float)N * (float)D));
}

// Round 6
// 122.177 us; speedup vs baseline: 18.5729x; 2.1684x over previous
//
#include <hip/hip_runtime.h>
#include <math.h>

typedef _Float16 v8h __attribute__((ext_vector_type(8)));
typedef float v4f __attribute__((ext_vector_type(4)));

constexpr int D      = 256;    // feature dim
constexpr int BM     = 128;    // rows per block (approx kernel)
constexpr int NT     = 32;     // codeword tiles (1024 / 32)
constexpr int TILE_B = 16384;  // bytes per staged tile (32 cw x 256 d x 2B fp16)

// ---- pre-pass: codewords -> fp16 in the pre-swizzled LDS-image layout ----
// Tile t (32 codewords), row c, 16B chunk cb: byte = t*TILE_B + c*512 + ((cb*16) ^ ((c&7)<<4))
__global__ void vq_prep(const float* __restrict__ cw, unsigned short* __restrict__ wsB) {
    int gid = blockIdx.x * 256 + threadIdx.x;   // 1024 cw * 32 chunks = 32768
    int k  = gid >> 5;
    int cb = gid & 31;
    const float* src = cw + (size_t)k * D + cb * 8;
    v8h vh;
    #pragma unroll
    for (int e = 0; e < 8; ++e) vh[e] = (_Float16)src[e];
    int t = k >> 5, c = k & 31;
    size_t base = (size_t)t * TILE_B + (size_t)c * 512 + (size_t)((cb * 16) ^ ((c & 7) << 4));
    *(v8h*)((char*)wsB + base) = vh;
}

// ---- codeword squared norms (fp32; IDENTICAL to the round-1/5 code that passed) ----
__global__ void vq_csq(const float* __restrict__ cw, float* __restrict__ csq) {
    int k = blockIdx.x * blockDim.x + threadIdx.x;
    const float4* p = reinterpret_cast<const float4*>(cw + (size_t)k * D);
    float s = 0.f;
    #pragma unroll 8
    for (int i = 0; i < D / 4; ++i) {
        float4 v = p[i];
        s += v.x * v.x; s += v.y * v.y; s += v.z * v.z; s += v.w * v.w;
    }
    csq[k] = s;
}

// ---- approx phase: fp16 MFMA -> packed per-lane top2 -> global top4 -> cand[] ----
__launch_bounds__(256, 2)
__global__ void vq_mfma(const float* __restrict__ inp,
                        const unsigned short* __restrict__ wsB,
                        const float* __restrict__ csq,
                        int* __restrict__ cand) {
    extern __shared__ char smem[];

    const int tid  = threadIdx.x;
    const int lane = tid & 63;
    const int w    = tid >> 6;      // wave 0..3
    const int lr   = lane & 15;     // frag row/col
    const int q    = lane >> 4;     // k-chunk group
    const int r0   = blockIdx.x * BM;

    // stage tile 0 into buf0 (linear copy of pre-swizzled image)
    #pragma unroll
    for (int cl = 0; cl < 4; ++cl) {
        int off = cl * 4096 + w * 1024;
        __builtin_amdgcn_global_load_lds(
            (const __attribute__((address_space(1))) unsigned int*)((const char*)wsB + off + lane * 16),
            (__attribute__((address_space(3))) unsigned int*)(smem + off),
            16, 0, 0);
    }

    // load this wave's 32 rows of A, convert to fp16 fragments in regs
    // A frag (16x16x32): lane holds row = lane&15, k = (lane>>4)*8 + e
    v8h a[2][8];
    #pragma unroll
    for (int m = 0; m < 2; ++m) {
        const float* rp = inp + (size_t)(r0 + w * 32 + m * 16 + lr) * D + q * 8;
        #pragma unroll
        for (int j = 0; j < 8; ++j) {
            float4 t0 = *(const float4*)(rp + j * 32);
            float4 t1 = *(const float4*)(rp + j * 32 + 4);
            v8h h;
            h[0] = (_Float16)t0.x; h[1] = (_Float16)t0.y;
            h[2] = (_Float16)t0.z; h[3] = (_Float16)t0.w;
            h[4] = (_Float16)t1.x; h[5] = (_Float16)t1.y;
            h[6] = (_Float16)t1.z; h[7] = (_Float16)t1.w;
            a[m][j] = h;
        }
    }

    asm volatile("s_waitcnt vmcnt(0)" ::: "memory");
    __builtin_amdgcn_s_barrier();
    __builtin_amdgcn_sched_barrier(0);

    // packed top-2 per lane: float whose low 10 bits carry the codeword index.
    // score = (csq + 4096) - 2*dot  (>= ~4000 > 0, fixed-exponent region, quant <= 0.5)
    const float BIGF = __uint_as_float(0x7F000000u);
    float t1v[2][4], t2v[2][4];
    #pragma unroll
    for (int m = 0; m < 2; ++m)
        #pragma unroll
        for (int r = 0; r < 4; ++r) { t1v[m][r] = BIGF; t2v[m][r] = BIGF; }

    int cur = 0;
    for (int kt = 0; kt < NT; ++kt) {
        if (kt + 1 < NT) {   // stage next tile early (2-phase template)
            const char* srct = (const char*)wsB + (size_t)(kt + 1) * TILE_B;
            char* dst = smem + (cur ^ 1) * TILE_B;
            #pragma unroll
            for (int cl = 0; cl < 4; ++cl) {
                int off = cl * 4096 + w * 1024;
                __builtin_amdgcn_global_load_lds(
                    (const __attribute__((address_space(1))) unsigned int*)(srct + off + lane * 16),
                    (__attribute__((address_space(3))) unsigned int*)(dst + off),
                    16, 0, 0);
            }
        }
        float cqb0 = csq[kt * 32 + lr] + 4096.f;
        float cqb1 = csq[kt * 32 + 16 + lr] + 4096.f;

        v4f acc[2][2];
        #pragma unroll
        for (int m = 0; m < 2; ++m)
            #pragma unroll
            for (int n = 0; n < 2; ++n) { v4f z = {0.f, 0.f, 0.f, 0.f}; acc[m][n] = z; }

        const char* bb = smem + cur * TILE_B;
        #pragma unroll
        for (int j = 0; j < 8; ++j) {
            v8h bh[2];
            #pragma unroll
            for (int n = 0; n < 2; ++n) {
                int c   = n * 16 + lr;
                int col = (j * 64 + q * 16) ^ ((c & 7) << 4);   // swizzled ds_read
                bh[n] = *(const v8h*)(bb + c * 512 + col);
            }
            #pragma unroll
            for (int m = 0; m < 2; ++m)
                #pragma unroll
                for (int n = 0; n < 2; ++n)
                    acc[m][n] = __builtin_amdgcn_mfma_f32_16x16x32_f16(a[m][j], bh[n], acc[m][n], 0, 0, 0);
        }

        // score + packed top-2 update (VALU only; runs while next tile stages)
        // C/D layout: col = lane&15, row = (lane>>4)*4 + r
        #pragma unroll
        for (int m = 0; m < 2; ++m)
            #pragma unroll
            for (int n = 0; n < 2; ++n) {
                int   idx = kt * 32 + n * 16 + lr;
                float cqb = n ? cqb1 : cqb0;
                #pragma unroll
                for (int r = 0; r < 4; ++r) {
                    float s = fmaf(-2.f, acc[m][n][r], cqb);
                    float f = __uint_as_float((__float_as_uint(s) & 0xFFFFFC00u) | (unsigned)idx);
                    float mx = fmaxf(t1v[m][r], f);
                    t2v[m][r] = fminf(t2v[m][r], mx);
                    t1v[m][r] = fminf(t1v[m][r], f);
                }
            }

        asm volatile("s_waitcnt vmcnt(0)" ::: "memory");   // next tile landed
        __builtin_amdgcn_s_barrier();
        __builtin_amdgcn_sched_barrier(0);
        cur ^= 1;
    }

    // bitonic merge of packed sorted-2 (padded to 4) across the 16 lanes per row
    #pragma unroll
    for (int m = 0; m < 2; ++m)
        #pragma unroll
        for (int r = 0; r < 4; ++r) {
            float L0 = t1v[m][r], L1 = t2v[m][r], L2 = BIGF, L3 = BIGF;
            #pragma unroll
            for (int off = 8; off; off >>= 1) {
                float P0 = __shfl_xor(L0, off, 16);
                float P1 = __shfl_xor(L1, off, 16);
                float P2 = __shfl_xor(L2, off, 16);
                float P3 = __shfl_xor(L3, off, 16);
                float M0 = fminf(L0, P3), M1 = fminf(L1, P2);
                float M2 = fminf(L2, P1), M3 = fminf(L3, P0);
                float a0 = fminf(M0, M2), c0 = fmaxf(M0, M2);
                float b0 = fminf(M1, M3), d0 = fmaxf(M1, M3);
                L0 = fminf(a0, b0); L1 = fmaxf(a0, b0);
                L2 = fminf(c0, d0); L3 = fmaxf(c0, d0);
            }
            if (lr == 0) {
                int row = w * 32 + m * 16 + q * 4 + r;
                ((int4*)cand)[r0 + row] = make_int4(
                    (int)(__float_as_uint(L0) & 1023u),
                    (int)(__float_as_uint(L1) & 1023u),
                    (int)(__float_as_uint(L2) & 1023u),
                    (int)(__float_as_uint(L3) & 1023u));
            }
        }
}

// ---- exact phase: round-1/5 arithmetic on the 4 candidates, 1 thread = 1 row ----
// dot & xsq: sequential fp32 FMA in ascending d (matches round 1/5 which passed).
// distance: (xsq - (dot+dot)) + csq[k]. Then coalesced gather/write of winners.
__launch_bounds__(256)
__global__ void vq_exact(const float* __restrict__ inp,
                         const float* __restrict__ cw,
                         const float* __restrict__ csq,
                         const int* __restrict__ cand,
                         float* __restrict__ outq,
                         float* __restrict__ outi,
                         float* __restrict__ bsum) {
    __shared__ int   s_bidx[256];
    __shared__ float s_l[4];
    const int tid  = threadIdx.x;
    const int lane = tid & 63;
    const int wv   = tid >> 6;
    const int row  = blockIdx.x * 256 + tid;

    int4 c4 = ((const int4*)cand)[row];
    int cd[4] = {c4.x, c4.y, c4.z, c4.w};

    const float4* xp = (const float4*)(inp + (size_t)row * D);
    float dot[4] = {0.f, 0.f, 0.f, 0.f};
    float xsq = 0.f;

    #pragma unroll 4
    for (int i = 0; i < D / 4; ++i) {
        float4 xv = xp[i];
        xsq = fmaf(xv.x, xv.x, xsq);
        xsq = fmaf(xv.y, xv.y, xsq);
        xsq = fmaf(xv.z, xv.z, xsq);
        xsq = fmaf(xv.w, xv.w, xsq);
        #pragma unroll
        for (int c = 0; c < 4; ++c) {
            float4 cv = *(const float4*)(cw + (size_t)cd[c] * D + i * 4);
            dot[c] = fmaf(xv.x, cv.x, dot[c]);
            dot[c] = fmaf(xv.y, cv.y, dot[c]);
            dot[c] = fmaf(xv.z, cv.z, dot[c]);
            dot[c] = fmaf(xv.w, cv.w, dot[c]);
        }
    }

    float bd = INFINITY;
    int   bi = 0x7FFFFFFF;
    #pragma unroll
    for (int c = 0; c < 4; ++c) {
        float m2 = dot[c] + dot[c];
        float t  = xsq - m2;
        float e  = t + csq[cd[c]];
        bool  tk = (e < bd) || (e == bd && cd[c] < bi);
        bd = tk ? e : bd;
        bi = tk ? cd[c] : bi;
    }
    s_bidx[tid] = bi;
    outi[row] = (float)bi;

    // loss partial = winner's exact distance
    float lacc = bd;
    #pragma unroll
    for (int off = 32; off; off >>= 1) lacc += __shfl_xor(lacc, off);
    if (lane == 0) s_l[wv] = lacc;
    __syncthreads();
    if (tid == 0) bsum[blockIdx.x] = s_l[0] + s_l[1] + s_l[2] + s_l[3];

    // coalesced gather of winning codewords -> outq (one row per wave per iter)
    for (int it = 0; it < 64; ++it) {
        int rr = it * 4 + wv;
        int k  = s_bidx[rr];                       // wave-uniform broadcast
        float4 cv = *(const float4*)(cw + (size_t)k * D + lane * 4);
        *(float4*)(outq + (size_t)(blockIdx.x * 256 + rr) * D + lane * 4) = cv;
    }
}

// ---- deterministic loss reduction ----
__global__ void vq_finalize(const float* __restrict__ bsum, float* __restrict__ out_loss,
                            int nb, float scale) {
    __shared__ float s[4];
    int tid = threadIdx.x;
    float v = 0.f;
    for (int i = tid; i < nb; i += 256) v += bsum[i];
    #pragma unroll
    for (int off = 32; off; off >>= 1) v += __shfl_down(v, off, 64);
    if ((tid & 63) == 0) s[tid >> 6] = v;
    __syncthreads();
    if (tid == 0) out_loss[0] = (s[0] + s[1] + s[2] + s[3]) * scale;
}

extern "C" void kernel_launch(void* const* d_in, const int* in_sizes, int n_in,
                              void* d_out, int out_size, void* d_ws, size_t ws_size,
                              hipStream_t stream) {
    const float* inp = (const float*)d_in[0];
    const float* cw  = (const float*)d_in[1];
    float* out = (float*)d_out;
    const int N = in_sizes[0] / D;   // 65536
    const int K = in_sizes[1] / D;   // 1024

    char* ws = (char*)d_ws;
    unsigned short* wsB = (unsigned short*)ws;            // 512 KB: 32 tiles x 16 KB
    float* csq  = (float*)(ws + (size_t)NT * TILE_B);     // 4 KB
    float* bsum = csq + K;                                // 1 KB (256 partials)
    int*   cand = (int*)(bsum + 256);                     // N*4 ints = 1 MB

    float* outq = out;
    float* outi = out + (size_t)N * D;
    float* outl = outi + N;

    vq_prep<<<dim3((K * 32) / 256), dim3(256), 0, stream>>>(cw, wsB);
    vq_csq<<<dim3(K / 256), dim3(256), 0, stream>>>(cw, csq);

    size_t lds_bytes = 2 * TILE_B;
    vq_mfma<<<dim3(N / BM), dim3(256), lds_bytes, stream>>>(inp, wsB, csq, cand);
    vq_exact<<<dim3(N / 256), dim3(256), 0, stream>>>(inp, cw, csq, cand, outq, outi, bsum);
    vq_finalize<<<dim3(1), dim3(256), 0, stream>>>(bsum, outl, N / 256,
                                                   1.25f / ((float)N * (float)D));
}

// Round 7
// 119.134 us; speedup vs baseline: 19.0473x; 1.0255x over previous
//
#include <hip/hip_runtime.h>
#include <math.h>

typedef _Float16 v8h __attribute__((ext_vector_type(8)));
typedef float v4f __attribute__((ext_vector_type(4)));

constexpr int D      = 256;    // feature dim
constexpr int BM     = 128;    // rows per block (approx kernel)
constexpr int NT     = 32;     // codeword tiles (1024 / 32)
constexpr int TILE_B = 16384;  // bytes per staged tile (32 cw x 256 d x 2B fp16)

// ---- pre-pass: codewords -> fp16 in the pre-swizzled LDS-image layout ----
// Tile t (32 codewords), row c, 16B chunk cb: byte = t*TILE_B + c*512 + ((cb*16) ^ ((c&7)<<4))
__global__ void vq_prep(const float* __restrict__ cw, unsigned short* __restrict__ wsB) {
    int gid = blockIdx.x * 256 + threadIdx.x;   // 1024 cw * 32 chunks = 32768
    int k  = gid >> 5;
    int cb = gid & 31;
    const float* src = cw + (size_t)k * D + cb * 8;
    v8h vh;
    #pragma unroll
    for (int e = 0; e < 8; ++e) vh[e] = (_Float16)src[e];
    int t = k >> 5, c = k & 31;
    size_t base = (size_t)t * TILE_B + (size_t)c * 512 + (size_t)((cb * 16) ^ ((c & 7) << 4));
    *(v8h*)((char*)wsB + base) = vh;
}

// ---- codeword squared norms (fp32; IDENTICAL to the round-1/5 code that passed) ----
__global__ void vq_csq(const float* __restrict__ cw, float* __restrict__ csq) {
    int k = blockIdx.x * blockDim.x + threadIdx.x;
    const float4* p = reinterpret_cast<const float4*>(cw + (size_t)k * D);
    float s = 0.f;
    #pragma unroll 8
    for (int i = 0; i < D / 4; ++i) {
        float4 v = p[i];
        s += v.x * v.x; s += v.y * v.y; s += v.z * v.z; s += v.w * v.w;
    }
    csq[k] = s;
}

// ---- approx phase: fp16 MFMA -> packed per-lane top2 -> global top4 -> cand[] ----
__launch_bounds__(256, 2)
__global__ void vq_mfma(const float* __restrict__ inp,
                        const unsigned short* __restrict__ wsB,
                        const float* __restrict__ csq,
                        int* __restrict__ cand) {
    extern __shared__ char smem[];

    const int tid  = threadIdx.x;
    const int lane = tid & 63;
    const int w    = tid >> 6;      // wave 0..3
    const int lr   = lane & 15;     // frag row/col
    const int q    = lane >> 4;     // k-chunk group
    const int r0   = blockIdx.x * BM;

    // stage tile 0 into buf0 (linear copy of pre-swizzled image)
    #pragma unroll
    for (int cl = 0; cl < 4; ++cl) {
        int off = cl * 4096 + w * 1024;
        __builtin_amdgcn_global_load_lds(
            (const __attribute__((address_space(1))) unsigned int*)((const char*)wsB + off + lane * 16),
            (__attribute__((address_space(3))) unsigned int*)(smem + off),
            16, 0, 0);
    }

    // load this wave's 32 rows of A, convert to fp16 fragments in regs
    // A frag (16x16x32): lane holds row = lane&15, k = (lane>>4)*8 + e
    v8h a[2][8];
    #pragma unroll
    for (int m = 0; m < 2; ++m) {
        const float* rp = inp + (size_t)(r0 + w * 32 + m * 16 + lr) * D + q * 8;
        #pragma unroll
        for (int j = 0; j < 8; ++j) {
            float4 t0 = *(const float4*)(rp + j * 32);
            float4 t1 = *(const float4*)(rp + j * 32 + 4);
            v8h h;
            h[0] = (_Float16)t0.x; h[1] = (_Float16)t0.y;
            h[2] = (_Float16)t0.z; h[3] = (_Float16)t0.w;
            h[4] = (_Float16)t1.x; h[5] = (_Float16)t1.y;
            h[6] = (_Float16)t1.z; h[7] = (_Float16)t1.w;
            a[m][j] = h;
        }
    }

    asm volatile("s_waitcnt vmcnt(0)" ::: "memory");
    __builtin_amdgcn_s_barrier();
    __builtin_amdgcn_sched_barrier(0);

    // packed top-2 per lane: float whose low 10 bits carry the codeword index.
    // score = (csq + 4096) - 2*dot  (>= ~4000 > 0, fixed-exponent region, quant <= 0.5)
    const float BIGF = __uint_as_float(0x7F000000u);
    float t1v[2][4], t2v[2][4];
    #pragma unroll
    for (int m = 0; m < 2; ++m)
        #pragma unroll
        for (int r = 0; r < 4; ++r) { t1v[m][r] = BIGF; t2v[m][r] = BIGF; }

    int cur = 0;
    for (int kt = 0; kt < NT; ++kt) {
        if (kt + 1 < NT) {   // stage next tile early (2-phase template)
            const char* srct = (const char*)wsB + (size_t)(kt + 1) * TILE_B;
            char* dst = smem + (cur ^ 1) * TILE_B;
            #pragma unroll
            for (int cl = 0; cl < 4; ++cl) {
                int off = cl * 4096 + w * 1024;
                __builtin_amdgcn_global_load_lds(
                    (const __attribute__((address_space(1))) unsigned int*)(srct + off + lane * 16),
                    (__attribute__((address_space(3))) unsigned int*)(dst + off),
                    16, 0, 0);
            }
        }
        float cqb0 = csq[kt * 32 + lr] + 4096.f;
        float cqb1 = csq[kt * 32 + 16 + lr] + 4096.f;

        v4f acc[2][2];
        #pragma unroll
        for (int m = 0; m < 2; ++m)
            #pragma unroll
            for (int n = 0; n < 2; ++n) { v4f z = {0.f, 0.f, 0.f, 0.f}; acc[m][n] = z; }

        const char* bb = smem + cur * TILE_B;
        #pragma unroll
        for (int j = 0; j < 8; ++j) {
            v8h bh[2];
            #pragma unroll
            for (int n = 0; n < 2; ++n) {
                int c   = n * 16 + lr;
                int col = (j * 64 + q * 16) ^ ((c & 7) << 4);   // swizzled ds_read
                bh[n] = *(const v8h*)(bb + c * 512 + col);
            }
            #pragma unroll
            for (int m = 0; m < 2; ++m)
                #pragma unroll
                for (int n = 0; n < 2; ++n)
                    acc[m][n] = __builtin_amdgcn_mfma_f32_16x16x32_f16(a[m][j], bh[n], acc[m][n], 0, 0, 0);
        }

        // score + packed top-2 update (VALU only; runs while next tile stages)
        // C/D layout: col = lane&15, row = (lane>>4)*4 + r
        #pragma unroll
        for (int m = 0; m < 2; ++m)
            #pragma unroll
            for (int n = 0; n < 2; ++n) {
                int   idx = kt * 32 + n * 16 + lr;
                float cqb = n ? cqb1 : cqb0;
                #pragma unroll
                for (int r = 0; r < 4; ++r) {
                    float s = fmaf(-2.f, acc[m][n][r], cqb);
                    float f = __uint_as_float((__float_as_uint(s) & 0xFFFFFC00u) | (unsigned)idx);
                    float mx = fmaxf(t1v[m][r], f);
                    t2v[m][r] = fminf(t2v[m][r], mx);
                    t1v[m][r] = fminf(t1v[m][r], f);
                }
            }

        asm volatile("s_waitcnt vmcnt(0)" ::: "memory");   // next tile landed
        __builtin_amdgcn_s_barrier();
        __builtin_amdgcn_sched_barrier(0);
        cur ^= 1;
    }

    // bitonic merge of packed sorted-2 (padded to 4) across the 16 lanes per row
    #pragma unroll
    for (int m = 0; m < 2; ++m)
        #pragma unroll
        for (int r = 0; r < 4; ++r) {
            float L0 = t1v[m][r], L1 = t2v[m][r], L2 = BIGF, L3 = BIGF;
            #pragma unroll
            for (int off = 8; off; off >>= 1) {
                float P0 = __shfl_xor(L0, off, 16);
                float P1 = __shfl_xor(L1, off, 16);
                float P2 = __shfl_xor(L2, off, 16);
                float P3 = __shfl_xor(L3, off, 16);
                float M0 = fminf(L0, P3), M1 = fminf(L1, P2);
                float M2 = fminf(L2, P1), M3 = fminf(L3, P0);
                float a0 = fminf(M0, M2), c0 = fmaxf(M0, M2);
                float b0 = fminf(M1, M3), d0 = fmaxf(M1, M3);
                L0 = fminf(a0, b0); L1 = fmaxf(a0, b0);
                L2 = fminf(c0, d0); L3 = fmaxf(c0, d0);
            }
            if (lr == 0) {
                int row = w * 32 + m * 16 + q * 4 + r;
                ((int4*)cand)[r0 + row] = make_int4(
                    (int)(__float_as_uint(L0) & 1023u),
                    (int)(__float_as_uint(L1) & 1023u),
                    (int)(__float_as_uint(L2) & 1023u),
                    (int)(__float_as_uint(L3) & 1023u));
            }
        }
}

// ---- exact phase: one lane per (row, candidate); 4-lane groups share a row ----
// Each lane's dot/xsq chain is bit-identical to the round-5/6 per-thread chain
// (sequential fp32 FMA, ascending d). Group argmin via shfl over a strict total
// order (e, idx) -> same winner as the sequential scan. Gather-write coalesced.
__launch_bounds__(256)
__global__ void vq_exact(const float* __restrict__ inp,
                         const float* __restrict__ cw,
                         const float* __restrict__ csq,
                         const int* __restrict__ cand,
                         float* __restrict__ outq,
                         float* __restrict__ outi,
                         float* __restrict__ bsum) {
    __shared__ float s_l[4];
    const int tid  = threadIdx.x;
    const int lane = tid & 63;
    const int wv   = tid >> 6;
    const int g    = blockIdx.x * 256 + tid;
    const int row  = g >> 2;        // 4 lanes per row
    const int c    = g & 3;

    const int cd = cand[(size_t)row * 4 + c];
    const float4* xp = (const float4*)(inp + (size_t)row * D);
    const float4* cp = (const float4*)(cw + (size_t)cd * D);

    float dot = 0.f, xsq = 0.f;
    #pragma unroll 8
    for (int i = 0; i < D / 4; ++i) {
        float4 xv = xp[i];
        float4 cv = cp[i];
        xsq = fmaf(xv.x, xv.x, xsq);
        xsq = fmaf(xv.y, xv.y, xsq);
        xsq = fmaf(xv.z, xv.z, xsq);
        xsq = fmaf(xv.w, xv.w, xsq);
        dot = fmaf(xv.x, cv.x, dot);
        dot = fmaf(xv.y, cv.y, dot);
        dot = fmaf(xv.z, cv.z, dot);
        dot = fmaf(xv.w, cv.w, dot);
    }

    float m2 = dot + dot;
    float t  = xsq - m2;
    float e  = t + csq[cd];

    // group-of-4 argmin (value asc, index tie-break) — total order, any
    // reduction order yields the unique minimum
    float bd = e; int bi = cd;
    #pragma unroll
    for (int off = 1; off <= 2; off <<= 1) {
        float ev = __shfl_xor(bd, off, 4);
        int   iv = __shfl_xor(bi, off, 4);
        bool  tk = (ev < bd) || (ev == bd && iv < bi);
        bd = tk ? ev : bd;
        bi = tk ? iv : bi;
    }

    if (c == 0) outi[row] = (float)bi;

    // loss partial = winner's exact distance (one contribution per row)
    float lc = (c == 0) ? bd : 0.f;
    #pragma unroll
    for (int off = 32; off; off >>= 1) lc += __shfl_xor(lc, off);
    if (lane == 0) s_l[wv] = lc;
    __syncthreads();
    if (tid == 0) bsum[blockIdx.x] = s_l[0] + s_l[1] + s_l[2] + s_l[3];

    // coalesced gather of winning codewords -> outq (wave handles its 16 rows)
    const int rowbase = blockIdx.x * 64 + wv * 16;
    #pragma unroll 4
    for (int rr = 0; rr < 16; ++rr) {
        int bw = __shfl(bi, rr * 4, 64);   // lanes rr*4..rr*4+3 hold identical bi
        float4 cv = *(const float4*)(cw + (size_t)bw * D + lane * 4);
        *(float4*)(outq + (size_t)(rowbase + rr) * D + lane * 4) = cv;
    }
}

// ---- deterministic loss reduction ----
__global__ void vq_finalize(const float* __restrict__ bsum, float* __restrict__ out_loss,
                            int nb, float scale) {
    __shared__ float s[4];
    int tid = threadIdx.x;
    float v = 0.f;
    for (int i = tid; i < nb; i += 256) v += bsum[i];
    #pragma unroll
    for (int off = 32; off; off >>= 1) v += __shfl_down(v, off, 64);
    if ((tid & 63) == 0) s[tid >> 6] = v;
    __syncthreads();
    if (tid == 0) out_loss[0] = (s[0] + s[1] + s[2] + s[3]) * scale;
}

extern "C" void kernel_launch(void* const* d_in, const int* in_sizes, int n_in,
                              void* d_out, int out_size, void* d_ws, size_t ws_size,
                              hipStream_t stream) {
    const float* inp = (const float*)d_in[0];
    const float* cw  = (const float*)d_in[1];
    float* out = (float*)d_out;
    const int N = in_sizes[0] / D;   // 65536
    const int K = in_sizes[1] / D;   // 1024

    char* ws = (char*)d_ws;
    unsigned short* wsB = (unsigned short*)ws;            // 512 KB: 32 tiles x 16 KB
    float* csq  = (float*)(ws + (size_t)NT * TILE_B);     // 4 KB
    float* bsum = csq + K;                                // 4 KB (1024 partials)
    int*   cand = (int*)(bsum + 1024);                    // N*4 ints = 1 MB

    float* outq = out;
    float* outi = out + (size_t)N * D;
    float* outl = outi + N;

    vq_prep<<<dim3((K * 32) / 256), dim3(256), 0, stream>>>(cw, wsB);
    vq_csq<<<dim3(K / 256), dim3(256), 0, stream>>>(cw, csq);

    size_t lds_bytes = 2 * TILE_B;
    vq_mfma<<<dim3(N / BM), dim3(256), lds_bytes, stream>>>(inp, wsB, csq, cand);
    // 4 lanes per row -> 4N threads -> N/64 blocks of 256
    vq_exact<<<dim3(N / 64), dim3(256), 0, stream>>>(inp, cw, csq, cand, outq, outi, bsum);
    vq_finalize<<<dim3(1), dim3(256), 0, stream>>>(bsum, outl, N / 64,
                                                   1.25f / ((float)N * (float)D));
}